// Round 1
// baseline (1058.817 us; speedup 1.0000x reference)
//
#include <hip/hip_runtime.h>
#include <cstdint>
#include <cstddef>

// ---------------------------------------------------------------------------
// TemporalGNN: 2x EvolveGCNH (TopK-pool -> GRU weight evolve -> GCNConv) + MLP
// N=100000 nodes, F=128, E=625000 edges, all fp32.
// ---------------------------------------------------------------------------

#define FDIM 128

__device__ __forceinline__ float wave_sum(float v) {
#pragma unroll
  for (int m = 32; m >= 1; m >>= 1) v += __shfl_xor(v, m, 64);
  return v;
}

__device__ __forceinline__ float sigmoidf_(float x) {
  return 1.0f / (1.0f + expf(-x));
}

// ordered-uint key: high 32 = monotone float map, low 32 = ~index (smaller idx wins ties)
__device__ __forceinline__ unsigned long long skey(float f, unsigned i) {
  unsigned u = __float_as_uint(f);
  u = (u & 0x80000000u) ? ~u : (u | 0x80000000u);
  return ((unsigned long long)u << 32) | (unsigned)(~i);
}

// ---------------- setup: degree, CSR build ----------------

__global__ void k_init_degcnt(float* deg, int* cnt, int n) {
  int i = blockIdx.x * blockDim.x + threadIdx.x;
  if (i < n) { deg[i] = 1.0f; cnt[i] = 0; }   // self-loop weight 1 pre-added
}

__global__ void k_edge_deg(const int* __restrict__ ei, const float* __restrict__ ew,
                           float* deg, int* cnt, int E) {
  int e = blockIdx.x * blockDim.x + threadIdx.x;
  if (e < E) {
    int c = ei[E + e];                         // col
    atomicAdd(&deg[c], ew[e]);
    atomicAdd(&cnt[c], 1);
  }
}

__global__ void k_dinv(const float* deg, float* dinv, int n) {
  int i = blockIdx.x * blockDim.x + threadIdx.x;
  if (i < n) dinv[i] = 1.0f / sqrtf(deg[i]);  // deg >= 1 always
}

__global__ void k_scan1(const int* __restrict__ cnt, int* bsum, int n) {
  __shared__ int s[256];
  int b = blockIdx.x, t = threadIdx.x;
  int base = b * 1024;
  int v = 0;
#pragma unroll
  for (int j = 0; j < 4; j++) { int i = base + j * 256 + t; if (i < n) v += cnt[i]; }
  s[t] = v; __syncthreads();
  for (int off = 128; off > 0; off >>= 1) { if (t < off) s[t] += s[t + off]; __syncthreads(); }
  if (t == 0) bsum[b] = s[0];
}

__global__ void k_scan2(int* bsum, int nb) {
  if (threadIdx.x == 0 && blockIdx.x == 0) {
    int run = 0;
    for (int b = 0; b < nb; b++) { int t = bsum[b]; bsum[b] = run; run += t; }
  }
}

__global__ __launch_bounds__(1024) void k_scan3(const int* __restrict__ cnt,
                                                const int* __restrict__ bsum,
                                                int* rstart, int* rnext, int n) {
  __shared__ int s[1024];
  int b = blockIdx.x, t = threadIdx.x;
  int i = b * 1024 + t;
  int v = (i < n) ? cnt[i] : 0;
  s[t] = v; __syncthreads();
  for (int off = 1; off < 1024; off <<= 1) {
    int tmp = (t >= off) ? s[t - off] : 0;
    __syncthreads();
    s[t] += tmp;
    __syncthreads();
  }
  if (i < n) { int ex = bsum[b] + s[t] - v; rstart[i] = ex; rnext[i] = ex; }
}

__global__ void k_fill(const int* __restrict__ ei, int* rnext, int* eidb, int E) {
  int e = blockIdx.x * blockDim.x + threadIdx.x;
  if (e < E) {
    int c = ei[E + e];
    int pos = atomicAdd(&rnext[c], 1);
    eidb[pos] = e;
  }
}

// fuse lin1+lin2: out = h @ v + cconst
__global__ void k_linfuse(const float* l1w, const float* l1b, const float* l2w,
                          const float* l2b, float* v, float* cc) {
  int t = threadIdx.x;
  if (t < 128) v[t] = l2w[0] * l1w[t] + l2w[1] * l1w[128 + t];
  if (t == 0) cc[0] = l2w[0] * l1b[0] + l2w[1] * l1b[1] + l2b[0];
}

// ---------------- per-layer: scores + top-k ----------------

__global__ void k_invnorm(const float* p, float* invn) {
  int l = threadIdx.x;                          // 64 threads
  float2 pv = ((const float2*)p)[l];
  float s = pv.x * pv.x + pv.y * pv.y;
  s = wave_sum(s);
  if (l == 0) invn[0] = 1.0f / sqrtf(s);
}

__global__ void k_score(const float* __restrict__ x, const float* __restrict__ p,
                        const float* __restrict__ invn, float* sc, int n) {
  int wv = threadIdx.x >> 6, l = threadIdx.x & 63;
  int i = blockIdx.x * 4 + wv;
  if (i >= n) return;
  const float2* x2 = (const float2*)(x + (size_t)i * FDIM);
  const float2* p2 = (const float2*)p;
  float2 a = x2[l], b = p2[l];
  float s = a.x * b.x + a.y * b.y;
  s = wave_sum(s);
  if (l == 0) sc[i] = s * invn[0];
}

__device__ __forceinline__ void bitonic_desc(unsigned long long* a, int M, int t, int nt) {
  for (int size = 2; size <= M; size <<= 1) {
    for (int stride = size >> 1; stride > 0; stride >>= 1) {
      __syncthreads();
      for (int i = t; i < M; i += nt) {
        int j = i ^ stride;
        if (j > i) {
          unsigned long long x = a[i], y = a[j];
          bool up = ((i & size) == 0);
          if (up ? (x < y) : (x > y)) { a[i] = y; a[j] = x; }
        }
      }
    }
  }
  __syncthreads();
}

__global__ __launch_bounds__(256) void k_top1(const float* __restrict__ sc,
                                              unsigned long long* cand, int n) {
  __shared__ unsigned long long a[4096];
  int t = threadIdx.x;
  int base = blockIdx.x * 4096;
#pragma unroll
  for (int j = 0; j < 16; j++) {
    int i = base + j * 256 + t;
    a[j * 256 + t] = (i < n) ? skey(sc[i], (unsigned)i) : 0ULL;
  }
  bitonic_desc(a, 4096, t, 256);
  if (t < 128) cand[blockIdx.x * 128 + t] = a[t];
}

__global__ __launch_bounds__(1024) void k_top2(const unsigned long long* __restrict__ cand,
                                               const float* __restrict__ sc, int ncand,
                                               int* tidx, float* ttanh) {
  __shared__ unsigned long long a[4096];
  int t = threadIdx.x;
#pragma unroll
  for (int j = 0; j < 4; j++) {
    int i = j * 1024 + t;
    a[i] = (i < ncand) ? cand[i] : 0ULL;
  }
  bitonic_desc(a, 4096, t, 1024);
  if (t < 128) {
    unsigned idx = ~(unsigned)(a[t]);
    tidx[t] = (int)idx;
    ttanh[t] = tanhf(sc[idx]);
  }
}

// ---------------- GRU weight evolve: W = GRUcell(x_tilde, h0) ----------------

__global__ __launch_bounds__(384) void k_gru(const float* __restrict__ xin,
                                             const int* __restrict__ tidx,
                                             const float* __restrict__ ttanh,
                                             const float* __restrict__ wih,
                                             const float* __restrict__ whh,
                                             const float* __restrict__ bih,
                                             const float* __restrict__ bhh,
                                             const float* __restrict__ h0,
                                             float* __restrict__ Wout) {
  __shared__ float xt[128], hs[128], gis[384], ghs[384];
  int r = blockIdx.x, t = threadIdx.x;
  if (t < 128) {
    int idx = tidx[r];
    xt[t] = xin[(size_t)idx * FDIM + t] * ttanh[r];
    hs[t] = h0[r * FDIM + t];
  }
  __syncthreads();
  float gi = bih[t], gh = bhh[t];
  const float4* wi4 = (const float4*)(wih + (size_t)t * FDIM);
  const float4* wh4 = (const float4*)(whh + (size_t)t * FDIM);
#pragma unroll 8
  for (int k = 0; k < 32; k++) {
    float4 av = wi4[k], bv = wh4[k];
    gi += av.x * xt[4 * k] + av.y * xt[4 * k + 1] + av.z * xt[4 * k + 2] + av.w * xt[4 * k + 3];
    gh += bv.x * hs[4 * k] + bv.y * hs[4 * k + 1] + bv.z * hs[4 * k + 2] + bv.w * hs[4 * k + 3];
  }
  gis[t] = gi; ghs[t] = gh;
  __syncthreads();
  if (t < 128) {
    float rg = sigmoidf_(gis[t] + ghs[t]);
    float zg = sigmoidf_(gis[t + 128] + ghs[t + 128]);
    float ng = tanhf(gis[t + 256] + rg * ghs[t + 256]);
    Wout[r * FDIM + t] = (1.0f - zg) * ng + zg * hs[t];
  }
}

// ---------------- big GEMM: Y[N,128] = X[N,128] @ W[128,128] ----------------
// block: 256 threads (16x16), 128 rows per block, 8x8 register tile / thread.

__global__ __launch_bounds__(256) void k_gemm(const float* __restrict__ X,
                                              const float* __restrict__ W,
                                              float* __restrict__ Y, int nrows) {
  __shared__ float Ws[16][128];
  __shared__ float Xs[16][132];   // padded: transpose-store bank fix
  int tid = threadIdx.x;
  int ty = tid >> 4, tx = tid & 15;
  int r0 = blockIdx.x * 128;
  float acc[8][8];
#pragma unroll
  for (int i = 0; i < 8; i++)
#pragma unroll
    for (int j = 0; j < 8; j++) acc[i][j] = 0.0f;

  int lr = tid >> 1;            // 0..127 row within tile
  int lk = (tid & 1) * 8;       // k sub-offset 0 or 8
  const bool rvalid = (r0 + lr) < nrows;

  for (int k0 = 0; k0 < 128; k0 += 16) {
    { // W chunk: 2048 contiguous floats
      const float4* src = (const float4*)(W + (size_t)k0 * 128);
      float4* dst = (float4*)(&Ws[0][0]);
      dst[tid] = src[tid];
      dst[tid + 256] = src[tid + 256];
    }
    { // X chunk, transposed into Xs[k][r]
      float4 v0, v1;
      if (rvalid) {
        const float4* sx = (const float4*)(X + (size_t)(r0 + lr) * FDIM + k0 + lk);
        v0 = sx[0]; v1 = sx[1];
      } else {
        v0 = make_float4(0.f, 0.f, 0.f, 0.f); v1 = v0;
      }
      Xs[lk + 0][lr] = v0.x; Xs[lk + 1][lr] = v0.y; Xs[lk + 2][lr] = v0.z; Xs[lk + 3][lr] = v0.w;
      Xs[lk + 4][lr] = v1.x; Xs[lk + 5][lr] = v1.y; Xs[lk + 6][lr] = v1.z; Xs[lk + 7][lr] = v1.w;
    }
    __syncthreads();
#pragma unroll
    for (int kk = 0; kk < 16; kk++) {
      float4 a0 = *(const float4*)&Xs[kk][ty * 8];
      float4 a1 = *(const float4*)&Xs[kk][ty * 8 + 4];
      float4 b0 = *(const float4*)&Ws[kk][tx * 8];
      float4 b1 = *(const float4*)&Ws[kk][tx * 8 + 4];
      float a[8] = {a0.x, a0.y, a0.z, a0.w, a1.x, a1.y, a1.z, a1.w};
      float b[8] = {b0.x, b0.y, b0.z, b0.w, b1.x, b1.y, b1.z, b1.w};
#pragma unroll
      for (int i = 0; i < 8; i++)
#pragma unroll
        for (int j = 0; j < 8; j++) acc[i][j] += a[i] * b[j];
    }
    __syncthreads();
  }
#pragma unroll
  for (int i = 0; i < 8; i++) {
    int rr = r0 + ty * 8 + i;
    if (rr < nrows) {
      float4* yp = (float4*)(Y + (size_t)rr * FDIM + tx * 8);
      yp[0] = make_float4(acc[i][0], acc[i][1], acc[i][2], acc[i][3]);
      yp[1] = make_float4(acc[i][4], acc[i][5], acc[i][6], acc[i][7]);
    }
  }
}

// ---------------- GCN gather (CSR by col) + ReLU (+ fused final MLP) ----------

template <int FINAL>
__global__ void k_gather(const float* __restrict__ xw, const int* __restrict__ ei,
                         const float* __restrict__ ew, const float* __restrict__ dinv,
                         const int* __restrict__ rstart, const int* __restrict__ rcnt,
                         const int* __restrict__ eidb, float* __restrict__ outH,
                         float* __restrict__ outF, const float* __restrict__ vvec,
                         const float* __restrict__ cc, int n, int E) {
  int wv = threadIdx.x >> 6, l = threadIdx.x & 63;
  int c = blockIdx.x * 4 + wv;
  if (c >= n) return;
  float dc = dinv[c];
  const float* xr = xw + (size_t)c * FDIM;
  float a0 = dc * dc * xr[l];
  float a1 = dc * dc * xr[64 + l];
  int st = rstart[c], cn = rcnt[c];
  for (int q = 0; q < cn; q++) {
    int e = eidb[st + q];
    int r = ei[e];
    float w = ew[e];
    float nm = dinv[r] * w * dc;
    const float* xs = xw + (size_t)r * FDIM;
    a0 += nm * xs[l];
    a1 += nm * xs[64 + l];
  }
  if (FINAL) {
    float t = fmaxf(a0, 0.0f) * vvec[l] + fmaxf(a1, 0.0f) * vvec[64 + l];
    t = wave_sum(t);
    if (l == 0) outF[c] = t + cc[0];
  } else {
    outH[(size_t)c * FDIM + l] = fmaxf(a0, 0.0f);
    outH[(size_t)c * FDIM + 64 + l] = fmaxf(a1, 0.0f);
  }
}

// ---------------------------------------------------------------------------

extern "C" void kernel_launch(void* const* d_in, const int* in_sizes, int n_in,
                              void* d_out, int out_size, void* d_ws, size_t ws_size,
                              hipStream_t stream) {
  const float* x    = (const float*)d_in[0];
  const int*   ei   = (const int*)d_in[1];
  const float* ew   = (const float*)d_in[2];
  const float* p1   = (const float*)d_in[3];
  const float* wih1 = (const float*)d_in[4];
  const float* whh1 = (const float*)d_in[5];
  const float* bih1 = (const float*)d_in[6];
  const float* bhh1 = (const float*)d_in[7];
  const float* h01  = (const float*)d_in[8];
  const float* p2   = (const float*)d_in[9];
  const float* wih2 = (const float*)d_in[10];
  const float* whh2 = (const float*)d_in[11];
  const float* bih2 = (const float*)d_in[12];
  const float* bhh2 = (const float*)d_in[13];
  const float* h02  = (const float*)d_in[14];
  const float* l1w  = (const float*)d_in[15];
  const float* l1b  = (const float*)d_in[16];
  const float* l2w  = (const float*)d_in[17];
  const float* l2b  = (const float*)d_in[18];
  float* out = (float*)d_out;

  const int N = in_sizes[0] / FDIM;
  const int E = in_sizes[2];

  // workspace layout
  size_t off = 0;
  auto alloc = [&](size_t bytes) -> char* {
    char* p = (char*)d_ws + off;
    off = (off + bytes + 255) & ~(size_t)255;
    return p;
  };
  float* scores = (float*)alloc((size_t)N * 4);
  unsigned long long* cand = (unsigned long long*)alloc(4096 * 8);
  int*   tidx  = (int*)alloc(128 * 4);
  float* ttanh = (float*)alloc(128 * 4);
  float* invn  = (float*)alloc(4);
  float* deg   = (float*)alloc((size_t)N * 4);
  float* dinv  = (float*)alloc((size_t)N * 4);
  int*   cnt   = (int*)alloc((size_t)N * 4);
  int*   rstart= (int*)alloc((size_t)N * 4);
  int*   rnext = (int*)alloc((size_t)N * 4);
  const int nb = (N + 1023) / 1024;
  int*   bsum  = (int*)alloc((size_t)nb * 4);
  int*   eidb  = (int*)alloc((size_t)E * 4);
  float* vvec  = (float*)alloc(128 * 4);
  float* cc    = (float*)alloc(4);
  float* Wg    = (float*)alloc(128 * 128 * 4);
  float* xw    = (float*)alloc((size_t)N * FDIM * 4);
  float* h1    = (float*)alloc((size_t)N * FDIM * 4);
  (void)ws_size; (void)n_in; (void)out_size;

  const int nch = (N + 4095) / 4096;
  const int ncand = nch * 128;

  // ---- setup: degrees + CSR (shared by both layers) ----
  k_init_degcnt<<<(N + 255) / 256, 256, 0, stream>>>(deg, cnt, N);
  k_edge_deg<<<(E + 255) / 256, 256, 0, stream>>>(ei, ew, deg, cnt, E);
  k_dinv<<<(N + 255) / 256, 256, 0, stream>>>(deg, dinv, N);
  k_scan1<<<nb, 256, 0, stream>>>(cnt, bsum, N);
  k_scan2<<<1, 64, 0, stream>>>(bsum, nb);
  k_scan3<<<nb, 1024, 0, stream>>>(cnt, bsum, rstart, rnext, N);
  k_fill<<<(E + 255) / 256, 256, 0, stream>>>(ei, rnext, eidb, E);
  k_linfuse<<<1, 128, 0, stream>>>(l1w, l1b, l2w, l2b, vvec, cc);

  // ---- layer 1 ----
  k_invnorm<<<1, 64, 0, stream>>>(p1, invn);
  k_score<<<(N + 3) / 4, 256, 0, stream>>>(x, p1, invn, scores, N);
  k_top1<<<nch, 256, 0, stream>>>(scores, cand, N);
  k_top2<<<1, 1024, 0, stream>>>(cand, scores, ncand, tidx, ttanh);
  k_gru<<<128, 384, 0, stream>>>(x, tidx, ttanh, wih1, whh1, bih1, bhh1, h01, Wg);
  k_gemm<<<(N + 127) / 128, 256, 0, stream>>>(x, Wg, xw, N);
  k_gather<0><<<(N + 3) / 4, 256, 0, stream>>>(xw, ei, ew, dinv, rstart, cnt, eidb,
                                               h1, nullptr, nullptr, nullptr, N, E);

  // ---- layer 2 (input h1) + fused final linear ----
  k_invnorm<<<1, 64, 0, stream>>>(p2, invn);
  k_score<<<(N + 3) / 4, 256, 0, stream>>>(h1, p2, invn, scores, N);
  k_top1<<<nch, 256, 0, stream>>>(scores, cand, N);
  k_top2<<<1, 1024, 0, stream>>>(cand, scores, ncand, tidx, ttanh);
  k_gru<<<128, 384, 0, stream>>>(h1, tidx, ttanh, wih2, whh2, bih2, bhh2, h02, Wg);
  k_gemm<<<(N + 127) / 128, 256, 0, stream>>>(h1, Wg, xw, N);
  k_gather<1><<<(N + 3) / 4, 256, 0, stream>>>(xw, ei, ew, dinv, rstart, cnt, eidb,
                                               nullptr, out, vvec, cc, N, E);
}

// Round 2
// 568.986 us; speedup vs baseline: 1.8609x; 1.8609x over previous
//
#include <hip/hip_runtime.h>
#include <cstdint>
#include <cstddef>

// ---------------------------------------------------------------------------
// TemporalGNN: 2x EvolveGCNH (TopK-pool -> GRU weight evolve -> GCNConv) + MLP
// N=100000 nodes, F=128, E=625000 edges, all fp32.
// R2: radix-select top-k (replaces bitonic full sort), payload-packed CSR,
//     float2 gather, layer-2 score fused into gather-1 epilogue.
// ---------------------------------------------------------------------------

#define FDIM 128

__device__ __forceinline__ float wave_sum(float v) {
#pragma unroll
  for (int m = 32; m >= 1; m >>= 1) v += __shfl_xor(v, m, 64);
  return v;
}

__device__ __forceinline__ float sigmoidf_(float x) {
  return 1.0f / (1.0f + expf(-x));
}

// monotone float->uint map (order-preserving)
__device__ __forceinline__ unsigned omap(float f) {
  unsigned u = __float_as_uint(f);
  return (u & 0x80000000u) ? ~u : (u | 0x80000000u);
}

// ---------------- setup: degree, CSR build ----------------

__global__ void k_init_degcnt(float* deg, int* cnt, int n) {
  int i = blockIdx.x * blockDim.x + threadIdx.x;
  if (i < n) { deg[i] = 1.0f; cnt[i] = 0; }   // self-loop weight 1 pre-added
}

__global__ void k_edge_deg(const int* __restrict__ ei, const float* __restrict__ ew,
                           float* deg, int* cnt, int E) {
  int e = blockIdx.x * blockDim.x + threadIdx.x;
  if (e < E) {
    int c = ei[E + e];                         // col
    atomicAdd(&deg[c], ew[e]);
    atomicAdd(&cnt[c], 1);
  }
}

__global__ void k_dinv(const float* deg, float* dinv, int n) {
  int i = blockIdx.x * blockDim.x + threadIdx.x;
  if (i < n) dinv[i] = 1.0f / sqrtf(deg[i]);  // deg >= 1 always
}

__global__ void k_scan1(const int* __restrict__ cnt, int* bsum, int n) {
  __shared__ int s[256];
  int b = blockIdx.x, t = threadIdx.x;
  int base = b * 1024;
  int v = 0;
#pragma unroll
  for (int j = 0; j < 4; j++) { int i = base + j * 256 + t; if (i < n) v += cnt[i]; }
  s[t] = v; __syncthreads();
  for (int off = 128; off > 0; off >>= 1) { if (t < off) s[t] += s[t + off]; __syncthreads(); }
  if (t == 0) bsum[b] = s[0];
}

__global__ void k_scan2(int* bsum, int nb) {
  if (threadIdx.x == 0 && blockIdx.x == 0) {
    int run = 0;
    for (int b = 0; b < nb; b++) { int t = bsum[b]; bsum[b] = run; run += t; }
  }
}

__global__ __launch_bounds__(1024) void k_scan3(const int* __restrict__ cnt,
                                                const int* __restrict__ bsum,
                                                int* rstart, int* rnext, int n) {
  __shared__ int s[1024];
  int b = blockIdx.x, t = threadIdx.x;
  int i = b * 1024 + t;
  int v = (i < n) ? cnt[i] : 0;
  s[t] = v; __syncthreads();
  for (int off = 1; off < 1024; off <<= 1) {
    int tmp = (t >= off) ? s[t - off] : 0;
    __syncthreads();
    s[t] += tmp;
    __syncthreads();
  }
  if (i < n) { int ex = bsum[b] + s[t] - v; rstart[i] = ex; rnext[i] = ex; }
}

// scatter edge payload (row, norm) into CSR slots
__global__ void k_fill(const int* __restrict__ ei, const float* __restrict__ ew,
                       const float* __restrict__ dinv, int* rnext, int2* pay, int E) {
  int e = blockIdx.x * blockDim.x + threadIdx.x;
  if (e < E) {
    int r = ei[e];
    int c = ei[E + e];
    float nm = dinv[r] * ew[e] * dinv[c];
    int pos = atomicAdd(&rnext[c], 1);
    pay[pos] = make_int2(r, __float_as_int(nm));
  }
}

// fuse lin1+lin2: out = h @ v + cconst
__global__ void k_linfuse(const float* l1w, const float* l1b, const float* l2w,
                          const float* l2b, float* v, float* cc) {
  int t = threadIdx.x;
  if (t < 128) v[t] = l2w[0] * l1w[t] + l2w[1] * l1w[128 + t];
  if (t == 0) cc[0] = l2w[0] * l1b[0] + l2w[1] * l1b[1] + l2b[0];
}

// ---------------- top-k via radix select ----------------

__global__ void k_zero(int* hist) {   // zero hist[65536] + csel (hist[65536])
  int i = blockIdx.x * blockDim.x + threadIdx.x;
  if (i < 65537) hist[i] = 0;
}

__global__ void k_invnorm(const float* p, float* invn) {
  int l = threadIdx.x;                          // 64 threads
  float2 pv = ((const float2*)p)[l];
  float s = pv.x * pv.x + pv.y * pv.y;
  s = wave_sum(s);
  if (l == 0) invn[0] = 1.0f / sqrtf(s);
}

__global__ void k_score(const float* __restrict__ x, const float* __restrict__ p,
                        const float* __restrict__ invn, float* sc, int* hist, int n) {
  int wv = threadIdx.x >> 6, l = threadIdx.x & 63;
  int i = blockIdx.x * 4 + wv;
  if (i >= n) return;
  float2 a = ((const float2*)(x + (size_t)i * FDIM))[l];
  float2 b = ((const float2*)p)[l];
  float s = a.x * b.x + a.y * b.y;
  s = wave_sum(s);
  if (l == 0) {
    s *= invn[0];
    sc[i] = s;
    atomicAdd(&hist[omap(s) >> 16], 1);
  }
}

// find threshold bin B = max{b : count(bins >= b) >= 128}
__global__ __launch_bounds__(1024) void k_findthr(const int* __restrict__ hist, int* thrb) {
  __shared__ int s[1024];
  int t = threadIdx.x;
  int tot = 0;
#pragma unroll
  for (int j = 0; j < 64; j++) tot += hist[t * 64 + j];
  s[t] = tot; __syncthreads();
  for (int off = 1; off < 1024; off <<= 1) {
    int v = (t + off < 1024) ? s[t + off] : 0;
    __syncthreads();
    s[t] += v;
    __syncthreads();
  }
  int base = (t + 1 < 1024) ? s[t + 1] : 0;
  if (base < 128 && base + tot >= 128) {
    int run = base;
    for (int j = 63; j >= 0; j--) {
      run += hist[t * 64 + j];
      if (run >= 128) { thrb[0] = t * 64 + j; break; }
    }
  }
}

__global__ void k_collect(const float* __restrict__ sc, const int* __restrict__ thrb,
                          unsigned long long* candk, int* csel, int n) {
  int i = blockIdx.x * blockDim.x + threadIdx.x;
  if (i >= n) return;
  unsigned u = omap(sc[i]);
  if ((int)(u >> 16) >= thrb[0]) {
    int pos = atomicAdd(csel, 1);
    if (pos < 4096) candk[pos] = ((unsigned long long)u << 32) | (unsigned)(~(unsigned)i);
  }
}

// sort candidates (desc, index-asc tiebreak baked into key), emit top 128
__global__ __launch_bounds__(1024) void k_sel(const unsigned long long* __restrict__ candk,
                                              const int* __restrict__ csel,
                                              int* tidx, float* ttanh) {
  __shared__ unsigned long long a[4096];
  int t = threadIdx.x;
  int nc = csel[0]; if (nc > 4096) nc = 4096;
  int M = 128; while (M < nc) M <<= 1;
  for (int i = t; i < M; i += 1024) a[i] = (i < nc) ? candk[i] : 0ULL;
  for (int size = 2; size <= M; size <<= 1) {
    for (int stride = size >> 1; stride > 0; stride >>= 1) {
      __syncthreads();
      for (int i = t; i < M; i += 1024) {
        int j = i ^ stride;
        if (j > i) {
          unsigned long long x = a[i], y = a[j];
          bool up = ((i & size) == 0);
          if (up ? (x < y) : (x > y)) { a[i] = y; a[j] = x; }
        }
      }
    }
  }
  __syncthreads();
  if (t < 128) {
    unsigned long long k = a[t];
    unsigned idx = ~(unsigned)k;
    unsigned hi = (unsigned)(k >> 32);
    unsigned u = (hi & 0x80000000u) ? (hi ^ 0x80000000u) : ~hi;
    tidx[t] = (int)idx;
    ttanh[t] = tanhf(__uint_as_float(u));
  }
}

// ---------------- GRU weight evolve: W = GRUcell(x_tilde, h0) ----------------

__global__ __launch_bounds__(384) void k_gru(const float* __restrict__ xin,
                                             const int* __restrict__ tidx,
                                             const float* __restrict__ ttanh,
                                             const float* __restrict__ wih,
                                             const float* __restrict__ whh,
                                             const float* __restrict__ bih,
                                             const float* __restrict__ bhh,
                                             const float* __restrict__ h0,
                                             float* __restrict__ Wout) {
  __shared__ float xt[128], hs[128], gis[384], ghs[384];
  int r = blockIdx.x, t = threadIdx.x;
  if (t < 128) {
    int idx = tidx[r];
    xt[t] = xin[(size_t)idx * FDIM + t] * ttanh[r];
    hs[t] = h0[r * FDIM + t];
  }
  __syncthreads();
  float gi = bih[t], gh = bhh[t];
  const float4* wi4 = (const float4*)(wih + (size_t)t * FDIM);
  const float4* wh4 = (const float4*)(whh + (size_t)t * FDIM);
#pragma unroll 8
  for (int k = 0; k < 32; k++) {
    float4 av = wi4[k], bv = wh4[k];
    gi += av.x * xt[4 * k] + av.y * xt[4 * k + 1] + av.z * xt[4 * k + 2] + av.w * xt[4 * k + 3];
    gh += bv.x * hs[4 * k] + bv.y * hs[4 * k + 1] + bv.z * hs[4 * k + 2] + bv.w * hs[4 * k + 3];
  }
  gis[t] = gi; ghs[t] = gh;
  __syncthreads();
  if (t < 128) {
    float rg = sigmoidf_(gis[t] + ghs[t]);
    float zg = sigmoidf_(gis[t + 128] + ghs[t + 128]);
    float ng = tanhf(gis[t + 256] + rg * ghs[t + 256]);
    Wout[r * FDIM + t] = (1.0f - zg) * ng + zg * hs[t];
  }
}

// ---------------- big GEMM: Y[N,128] = X[N,128] @ W[128,128] ----------------

__global__ __launch_bounds__(256) void k_gemm(const float* __restrict__ X,
                                              const float* __restrict__ W,
                                              float* __restrict__ Y, int nrows) {
  __shared__ float Ws[16][128];
  __shared__ float Xs[16][132];   // padded: transpose-store bank fix
  int tid = threadIdx.x;
  int ty = tid >> 4, tx = tid & 15;
  int r0 = blockIdx.x * 128;
  float acc[8][8];
#pragma unroll
  for (int i = 0; i < 8; i++)
#pragma unroll
    for (int j = 0; j < 8; j++) acc[i][j] = 0.0f;

  int lr = tid >> 1;            // 0..127 row within tile
  int lk = (tid & 1) * 8;       // k sub-offset 0 or 8
  const bool rvalid = (r0 + lr) < nrows;

  for (int k0 = 0; k0 < 128; k0 += 16) {
    { // W chunk: 2048 contiguous floats
      const float4* src = (const float4*)(W + (size_t)k0 * 128);
      float4* dst = (float4*)(&Ws[0][0]);
      dst[tid] = src[tid];
      dst[tid + 256] = src[tid + 256];
    }
    { // X chunk, transposed into Xs[k][r]
      float4 v0, v1;
      if (rvalid) {
        const float4* sx = (const float4*)(X + (size_t)(r0 + lr) * FDIM + k0 + lk);
        v0 = sx[0]; v1 = sx[1];
      } else {
        v0 = make_float4(0.f, 0.f, 0.f, 0.f); v1 = v0;
      }
      Xs[lk + 0][lr] = v0.x; Xs[lk + 1][lr] = v0.y; Xs[lk + 2][lr] = v0.z; Xs[lk + 3][lr] = v0.w;
      Xs[lk + 4][lr] = v1.x; Xs[lk + 5][lr] = v1.y; Xs[lk + 6][lr] = v1.z; Xs[lk + 7][lr] = v1.w;
    }
    __syncthreads();
#pragma unroll
    for (int kk = 0; kk < 16; kk++) {
      float4 a0 = *(const float4*)&Xs[kk][ty * 8];
      float4 a1 = *(const float4*)&Xs[kk][ty * 8 + 4];
      float4 b0 = *(const float4*)&Ws[kk][tx * 8];
      float4 b1 = *(const float4*)&Ws[kk][tx * 8 + 4];
      float a[8] = {a0.x, a0.y, a0.z, a0.w, a1.x, a1.y, a1.z, a1.w};
      float b[8] = {b0.x, b0.y, b0.z, b0.w, b1.x, b1.y, b1.z, b1.w};
#pragma unroll
      for (int i = 0; i < 8; i++)
#pragma unroll
        for (int j = 0; j < 8; j++) acc[i][j] += a[i] * b[j];
    }
    __syncthreads();
  }
#pragma unroll
  for (int i = 0; i < 8; i++) {
    int rr = r0 + ty * 8 + i;
    if (rr < nrows) {
      float4* yp = (float4*)(Y + (size_t)rr * FDIM + tx * 8);
      yp[0] = make_float4(acc[i][0], acc[i][1], acc[i][2], acc[i][3]);
      yp[1] = make_float4(acc[i][4], acc[i][5], acc[i][6], acc[i][7]);
    }
  }
}

// ---------------- GCN gather (CSR payload) + ReLU + fused epilogues ----------
// FUSE=0: write h1, compute layer-2 score+hist.  FUSE=1: final MLP to out.

template <int FUSE>
__global__ void k_gather(const float* __restrict__ xw, const float* __restrict__ dinv,
                         const int* __restrict__ rstart, const int* __restrict__ rcnt,
                         const int2* __restrict__ pay, float* __restrict__ outH,
                         float* __restrict__ outF,
                         const float* __restrict__ p2, const float* __restrict__ invn2,
                         float* __restrict__ sc, int* __restrict__ hist,
                         const float* __restrict__ vvec, const float* __restrict__ cc,
                         int n) {
  int wv = threadIdx.x >> 6, l = threadIdx.x & 63;
  int c = blockIdx.x * 4 + wv;
  if (c >= n) return;
  float dc = dinv[c];
  float2 v = ((const float2*)(xw + (size_t)c * FDIM))[l];
  float ax = dc * dc * v.x, ay = dc * dc * v.y;
  int st = rstart[c], cn = rcnt[c];
  for (int q0 = 0; q0 < cn; q0 += 64) {
    int2 ep = (q0 + l < cn) ? pay[st + q0 + l] : make_int2(0, 0);
    int m = min(64, cn - q0);
    for (int q = 0; q < m; q++) {
      int r = __shfl(ep.x, q, 64);
      float nm = __int_as_float(__shfl(ep.y, q, 64));
      float2 s = ((const float2*)(xw + (size_t)r * FDIM))[l];
      ax += nm * s.x; ay += nm * s.y;
    }
  }
  float r0 = fmaxf(ax, 0.0f), r1 = fmaxf(ay, 0.0f);
  if (FUSE == 0) {
    ((float2*)(outH + (size_t)c * FDIM))[l] = make_float2(r0, r1);
    float2 pv = ((const float2*)p2)[l];
    float s = r0 * pv.x + r1 * pv.y;
    s = wave_sum(s);
    if (l == 0) {
      s *= invn2[0];
      sc[c] = s;
      atomicAdd(&hist[omap(s) >> 16], 1);
    }
  } else {
    float2 vv = ((const float2*)vvec)[l];
    float s = r0 * vv.x + r1 * vv.y;
    s = wave_sum(s);
    if (l == 0) outF[c] = s + cc[0];
  }
}

// ---------------------------------------------------------------------------

extern "C" void kernel_launch(void* const* d_in, const int* in_sizes, int n_in,
                              void* d_out, int out_size, void* d_ws, size_t ws_size,
                              hipStream_t stream) {
  const float* x    = (const float*)d_in[0];
  const int*   ei   = (const int*)d_in[1];
  const float* ew   = (const float*)d_in[2];
  const float* p1   = (const float*)d_in[3];
  const float* wih1 = (const float*)d_in[4];
  const float* whh1 = (const float*)d_in[5];
  const float* bih1 = (const float*)d_in[6];
  const float* bhh1 = (const float*)d_in[7];
  const float* h01  = (const float*)d_in[8];
  const float* p2   = (const float*)d_in[9];
  const float* wih2 = (const float*)d_in[10];
  const float* whh2 = (const float*)d_in[11];
  const float* bih2 = (const float*)d_in[12];
  const float* bhh2 = (const float*)d_in[13];
  const float* h02  = (const float*)d_in[14];
  const float* l1w  = (const float*)d_in[15];
  const float* l1b  = (const float*)d_in[16];
  const float* l2w  = (const float*)d_in[17];
  const float* l2b  = (const float*)d_in[18];
  float* out = (float*)d_out;

  const int N = in_sizes[0] / FDIM;
  const int E = in_sizes[2];

  // workspace layout
  size_t off = 0;
  auto alloc = [&](size_t bytes) -> char* {
    char* p = (char*)d_ws + off;
    off = (off + bytes + 255) & ~(size_t)255;
    return p;
  };
  float* scores = (float*)alloc((size_t)N * 4);
  unsigned long long* candk = (unsigned long long*)alloc(4096 * 8);
  int*   tidx  = (int*)alloc(128 * 4);
  float* ttanh = (float*)alloc(128 * 4);
  float* invn1 = (float*)alloc(4);
  float* invn2 = (float*)alloc(4);
  float* deg   = (float*)alloc((size_t)N * 4);   // aliased by hist after k_dinv
  float* dinv  = (float*)alloc((size_t)N * 4);
  int*   cnt   = (int*)alloc((size_t)N * 4);
  int*   rstart= (int*)alloc((size_t)N * 4);
  int*   rnext = (int*)alloc((size_t)N * 4);
  const int nb = (N + 1023) / 1024;
  int*   bsum  = (int*)alloc((size_t)nb * 4);
  int2*  pay   = (int2*)alloc((size_t)E * 8);
  float* vvec  = (float*)alloc(128 * 4);
  float* cc    = (float*)alloc(4);
  float* Wg    = (float*)alloc(128 * 128 * 4);
  float* xw    = (float*)alloc((size_t)N * FDIM * 4);
  float* h1    = (float*)alloc((size_t)N * FDIM * 4);
  (void)ws_size; (void)n_in; (void)out_size;

  int* hist = (int*)deg;          // 65536 bins + csel, fits in deg's N*4 bytes
  int* csel = hist + 65536;

  // ---- setup: degrees + CSR payload (shared by both layers) ----
  k_init_degcnt<<<(N + 255) / 256, 256, 0, stream>>>(deg, cnt, N);
  k_edge_deg<<<(E + 255) / 256, 256, 0, stream>>>(ei, ew, deg, cnt, E);
  k_dinv<<<(N + 255) / 256, 256, 0, stream>>>(deg, dinv, N);
  k_scan1<<<nb, 256, 0, stream>>>(cnt, bsum, N);
  k_scan2<<<1, 64, 0, stream>>>(bsum, nb);
  k_scan3<<<nb, 1024, 0, stream>>>(cnt, bsum, rstart, rnext, N);
  k_fill<<<(E + 255) / 256, 256, 0, stream>>>(ei, ew, dinv, rnext, pay, E);
  k_linfuse<<<1, 128, 0, stream>>>(l1w, l1b, l2w, l2b, vvec, cc);
  k_invnorm<<<1, 64, 0, stream>>>(p1, invn1);
  k_invnorm<<<1, 64, 0, stream>>>(p2, invn2);

  // ---- layer 1 ----
  k_zero<<<257, 256, 0, stream>>>(hist);
  k_score<<<(N + 3) / 4, 256, 0, stream>>>(x, p1, invn1, scores, hist, N);
  k_findthr<<<1, 1024, 0, stream>>>(hist, csel + 1);   // thrb stored next to csel? no:
  // NOTE: thrb must not alias csel (csel zeroed per layer). Use candk tail slot.
  // (see k_collect call below — thrb pointer = (int*)(candk + 4095) is unused cand slot)
  k_collect<<<(N + 255) / 256, 256, 0, stream>>>(scores, csel + 1, candk, csel, N);
  k_sel<<<1, 1024, 0, stream>>>(candk, csel, tidx, ttanh);
  k_gru<<<128, 384, 0, stream>>>(x, tidx, ttanh, wih1, whh1, bih1, bhh1, h01, Wg);
  k_gemm<<<(N + 127) / 128, 256, 0, stream>>>(x, Wg, xw, N);
  k_zero<<<257, 256, 0, stream>>>(hist);
  k_gather<0><<<(N + 3) / 4, 256, 0, stream>>>(xw, dinv, rstart, cnt, pay, h1, nullptr,
                                               p2, invn2, scores, hist, nullptr, nullptr, N);

  // ---- layer 2 + fused final linear ----
  k_findthr<<<1, 1024, 0, stream>>>(hist, csel + 1);
  k_collect<<<(N + 255) / 256, 256, 0, stream>>>(scores, csel + 1, candk, csel, N);
  k_sel<<<1, 1024, 0, stream>>>(candk, csel, tidx, ttanh);
  k_gru<<<128, 384, 0, stream>>>(h1, tidx, ttanh, wih2, whh2, bih2, bhh2, h02, Wg);
  k_gemm<<<(N + 127) / 128, 256, 0, stream>>>(h1, Wg, xw, N);
  k_gather<1><<<(N + 3) / 4, 256, 0, stream>>>(xw, dinv, rstart, cnt, pay, nullptr, out,
                                               nullptr, nullptr, nullptr, nullptr, vvec, cc, N);
}

// Round 3
// 518.909 us; speedup vs baseline: 2.0405x; 1.0965x over previous
//
#include <hip/hip_runtime.h>
#include <cstdint>
#include <cstddef>

// ---------------------------------------------------------------------------
// TemporalGNN: 2x EvolveGCNH (TopK-pool -> GRU weight evolve -> GCNConv) + MLP
// N=100000 nodes, F=128, E=625000 edges, all fp32.
// R3: GEMM moved to MFMA (3-pass bf16 split emulating fp32), no LDS in GEMM.
// ---------------------------------------------------------------------------

#define FDIM 128

typedef __attribute__((ext_vector_type(8))) short bfrag;   // 8 bf16 (4 VGPRs)
typedef __attribute__((ext_vector_type(4))) float f32x4;

__device__ __forceinline__ float wave_sum(float v) {
#pragma unroll
  for (int m = 32; m >= 1; m >>= 1) v += __shfl_xor(v, m, 64);
  return v;
}

__device__ __forceinline__ float sigmoidf_(float x) {
  return 1.0f / (1.0f + expf(-x));
}

// monotone float->uint map (order-preserving)
__device__ __forceinline__ unsigned omap(float f) {
  unsigned u = __float_as_uint(f);
  return (u & 0x80000000u) ? ~u : (u | 0x80000000u);
}

// ---------------- setup: degree, CSR build ----------------

__global__ void k_init_degcnt(float* deg, int* cnt, int n) {
  int i = blockIdx.x * blockDim.x + threadIdx.x;
  if (i < n) { deg[i] = 1.0f; cnt[i] = 0; }   // self-loop weight 1 pre-added
}

__global__ void k_edge_deg(const int* __restrict__ ei, const float* __restrict__ ew,
                           float* deg, int* cnt, int E) {
  int e = blockIdx.x * blockDim.x + threadIdx.x;
  if (e < E) {
    int c = ei[E + e];                         // col
    atomicAdd(&deg[c], ew[e]);
    atomicAdd(&cnt[c], 1);
  }
}

__global__ void k_dinv(const float* deg, float* dinv, int n) {
  int i = blockIdx.x * blockDim.x + threadIdx.x;
  if (i < n) dinv[i] = 1.0f / sqrtf(deg[i]);  // deg >= 1 always
}

__global__ void k_scan1(const int* __restrict__ cnt, int* bsum, int n) {
  __shared__ int s[256];
  int b = blockIdx.x, t = threadIdx.x;
  int base = b * 1024;
  int v = 0;
#pragma unroll
  for (int j = 0; j < 4; j++) { int i = base + j * 256 + t; if (i < n) v += cnt[i]; }
  s[t] = v; __syncthreads();
  for (int off = 128; off > 0; off >>= 1) { if (t < off) s[t] += s[t + off]; __syncthreads(); }
  if (t == 0) bsum[b] = s[0];
}

__global__ void k_scan2(int* bsum, int nb) {
  if (threadIdx.x == 0 && blockIdx.x == 0) {
    int run = 0;
    for (int b = 0; b < nb; b++) { int t = bsum[b]; bsum[b] = run; run += t; }
  }
}

__global__ __launch_bounds__(1024) void k_scan3(const int* __restrict__ cnt,
                                                const int* __restrict__ bsum,
                                                int* rstart, int* rnext, int n) {
  __shared__ int s[1024];
  int b = blockIdx.x, t = threadIdx.x;
  int i = b * 1024 + t;
  int v = (i < n) ? cnt[i] : 0;
  s[t] = v; __syncthreads();
  for (int off = 1; off < 1024; off <<= 1) {
    int tmp = (t >= off) ? s[t - off] : 0;
    __syncthreads();
    s[t] += tmp;
    __syncthreads();
  }
  if (i < n) { int ex = bsum[b] + s[t] - v; rstart[i] = ex; rnext[i] = ex; }
}

// scatter edge payload (row, norm) into CSR slots
__global__ void k_fill(const int* __restrict__ ei, const float* __restrict__ ew,
                       const float* __restrict__ dinv, int* rnext, int2* pay, int E) {
  int e = blockIdx.x * blockDim.x + threadIdx.x;
  if (e < E) {
    int r = ei[e];
    int c = ei[E + e];
    float nm = dinv[r] * ew[e] * dinv[c];
    int pos = atomicAdd(&rnext[c], 1);
    pay[pos] = make_int2(r, __float_as_int(nm));
  }
}

// fuse lin1+lin2: out = h @ v + cconst
__global__ void k_linfuse(const float* l1w, const float* l1b, const float* l2w,
                          const float* l2b, float* v, float* cc) {
  int t = threadIdx.x;
  if (t < 128) v[t] = l2w[0] * l1w[t] + l2w[1] * l1w[128 + t];
  if (t == 0) cc[0] = l2w[0] * l1b[0] + l2w[1] * l1b[1] + l2b[0];
}

// ---------------- top-k via radix select ----------------

__global__ void k_zero(int* hist) {   // zero hist[65536] + csel (hist[65536])
  int i = blockIdx.x * blockDim.x + threadIdx.x;
  if (i < 65537) hist[i] = 0;
}

__global__ void k_invnorm(const float* p, float* invn) {
  int l = threadIdx.x;                          // 64 threads
  float2 pv = ((const float2*)p)[l];
  float s = pv.x * pv.x + pv.y * pv.y;
  s = wave_sum(s);
  if (l == 0) invn[0] = 1.0f / sqrtf(s);
}

__global__ void k_score(const float* __restrict__ x, const float* __restrict__ p,
                        const float* __restrict__ invn, float* sc, int* hist, int n) {
  int wv = threadIdx.x >> 6, l = threadIdx.x & 63;
  int i = blockIdx.x * 4 + wv;
  if (i >= n) return;
  float2 a = ((const float2*)(x + (size_t)i * FDIM))[l];
  float2 b = ((const float2*)p)[l];
  float s = a.x * b.x + a.y * b.y;
  s = wave_sum(s);
  if (l == 0) {
    s *= invn[0];
    sc[i] = s;
    atomicAdd(&hist[omap(s) >> 16], 1);
  }
}

// find threshold bin B = max{b : count(bins >= b) >= 128}
__global__ __launch_bounds__(1024) void k_findthr(const int* __restrict__ hist, int* thrb) {
  __shared__ int s[1024];
  int t = threadIdx.x;
  int tot = 0;
#pragma unroll
  for (int j = 0; j < 64; j++) tot += hist[t * 64 + j];
  s[t] = tot; __syncthreads();
  for (int off = 1; off < 1024; off <<= 1) {
    int v = (t + off < 1024) ? s[t + off] : 0;
    __syncthreads();
    s[t] += v;
    __syncthreads();
  }
  int base = (t + 1 < 1024) ? s[t + 1] : 0;
  if (base < 128 && base + tot >= 128) {
    int run = base;
    for (int j = 63; j >= 0; j--) {
      run += hist[t * 64 + j];
      if (run >= 128) { thrb[0] = t * 64 + j; break; }
    }
  }
}

__global__ void k_collect(const float* __restrict__ sc, const int* __restrict__ thrb,
                          unsigned long long* candk, int* csel, int n) {
  int i = blockIdx.x * blockDim.x + threadIdx.x;
  if (i >= n) return;
  unsigned u = omap(sc[i]);
  if ((int)(u >> 16) >= thrb[0]) {
    int pos = atomicAdd(csel, 1);
    if (pos < 4096) candk[pos] = ((unsigned long long)u << 32) | (unsigned)(~(unsigned)i);
  }
}

// sort candidates (desc, index-asc tiebreak baked into key), emit top 128
__global__ __launch_bounds__(1024) void k_sel(const unsigned long long* __restrict__ candk,
                                              const int* __restrict__ csel,
                                              int* tidx, float* ttanh) {
  __shared__ unsigned long long a[4096];
  int t = threadIdx.x;
  int nc = csel[0]; if (nc > 4096) nc = 4096;
  int M = 128; while (M < nc) M <<= 1;
  for (int i = t; i < M; i += 1024) a[i] = (i < nc) ? candk[i] : 0ULL;
  for (int size = 2; size <= M; size <<= 1) {
    for (int stride = size >> 1; stride > 0; stride >>= 1) {
      __syncthreads();
      for (int i = t; i < M; i += 1024) {
        int j = i ^ stride;
        if (j > i) {
          unsigned long long x = a[i], y = a[j];
          bool up = ((i & size) == 0);
          if (up ? (x < y) : (x > y)) { a[i] = y; a[j] = x; }
        }
      }
    }
  }
  __syncthreads();
  if (t < 128) {
    unsigned long long k = a[t];
    unsigned idx = ~(unsigned)k;
    unsigned hi = (unsigned)(k >> 32);
    unsigned u = (hi & 0x80000000u) ? (hi ^ 0x80000000u) : ~hi;
    tidx[t] = (int)idx;
    ttanh[t] = tanhf(__uint_as_float(u));
  }
}

// ---------------- GRU weight evolve -> bf16-split transposed weights --------
// Writes WT_hi[j][k], WT_lo[j][k] (bf16) with W[k][j] = hi + lo, for MFMA B-frags.

__global__ __launch_bounds__(384) void k_gru(const float* __restrict__ xin,
                                             const int* __restrict__ tidx,
                                             const float* __restrict__ ttanh,
                                             const float* __restrict__ wih,
                                             const float* __restrict__ whh,
                                             const float* __restrict__ bih,
                                             const float* __restrict__ bhh,
                                             const float* __restrict__ h0,
                                             unsigned short* __restrict__ WT_hi,
                                             unsigned short* __restrict__ WT_lo) {
  __shared__ float xt[128], hs[128], gis[384], ghs[384];
  int r = blockIdx.x, t = threadIdx.x;
  if (t < 128) {
    int idx = tidx[r];
    xt[t] = xin[(size_t)idx * FDIM + t] * ttanh[r];
    hs[t] = h0[r * FDIM + t];
  }
  __syncthreads();
  float gi = bih[t], gh = bhh[t];
  const float4* wi4 = (const float4*)(wih + (size_t)t * FDIM);
  const float4* wh4 = (const float4*)(whh + (size_t)t * FDIM);
#pragma unroll 8
  for (int k = 0; k < 32; k++) {
    float4 av = wi4[k], bv = wh4[k];
    gi += av.x * xt[4 * k] + av.y * xt[4 * k + 1] + av.z * xt[4 * k + 2] + av.w * xt[4 * k + 3];
    gh += bv.x * hs[4 * k] + bv.y * hs[4 * k + 1] + bv.z * hs[4 * k + 2] + bv.w * hs[4 * k + 3];
  }
  gis[t] = gi; ghs[t] = gh;
  __syncthreads();
  if (t < 128) {
    float rg = sigmoidf_(gis[t] + ghs[t]);
    float zg = sigmoidf_(gis[t + 128] + ghs[t + 128]);
    float ng = tanhf(gis[t + 256] + rg * ghs[t + 256]);
    float w = (1.0f - zg) * ng + zg * hs[t];
    unsigned u = __float_as_uint(w);
    float res = w - __uint_as_float(u & 0xFFFF0000u);
    WT_hi[t * FDIM + r] = (unsigned short)(u >> 16);
    WT_lo[t * FDIM + r] = (unsigned short)(__float_as_uint(res) >> 16);
  }
}

// ---------------- big GEMM via MFMA: Y[N,128] = X[N,128] @ W[128,128] -------
// 3-pass bf16 split: Y = Xh*Wh + Xh*Wl + Xl*Wh  (error ~2^-16 rel).
// One wave per 16-row tile; A-frags loaded fp32 from global + split in-reg;
// B-frags from pre-transposed bf16 WT (L1/L2-hot). No LDS.

__global__ __launch_bounds__(256) void k_gemm3(const float* __restrict__ X,
                                               const unsigned short* __restrict__ BTh,
                                               const unsigned short* __restrict__ BTl,
                                               float* __restrict__ Y, int nrows) {
  int tid = threadIdx.x;
  int wv = tid >> 6, l = tid & 63;
  int tile = blockIdx.x * 4 + wv;
  int ntiles = (nrows + 15) >> 4;
  if (tile >= ntiles) return;
  int r0 = tile * 16;
  int arow = r0 + (l & 15);
  if (arow >= nrows) arow = nrows - 1;     // clamp; guarded at store
  int kgrp = (l >> 4) * 8;

  f32x4 acc[8];
#pragma unroll
  for (int c = 0; c < 8; c++) acc[c] = (f32x4){0.f, 0.f, 0.f, 0.f};

  const float* xp = X + (size_t)arow * FDIM + kgrp;

#pragma unroll
  for (int ks = 0; ks < 4; ks++) {
    float4 v0 = *(const float4*)(xp + ks * 32);
    float4 v1 = *(const float4*)(xp + ks * 32 + 4);
    float xs[8] = {v0.x, v0.y, v0.z, v0.w, v1.x, v1.y, v1.z, v1.w};
    bfrag ah, al;
#pragma unroll
    for (int i = 0; i < 8; i++) {
      unsigned u = __float_as_uint(xs[i]);
      float res = xs[i] - __uint_as_float(u & 0xFFFF0000u);
      ah[i] = (short)(u >> 16);
      al[i] = (short)(__float_as_uint(res) >> 16);
    }
#pragma unroll
    for (int ct = 0; ct < 8; ct++) {
      size_t boff = (size_t)(ct * 16 + (l & 15)) * FDIM + ks * 32 + kgrp;
      bfrag bh = *(const bfrag*)(BTh + boff);
      bfrag bl = *(const bfrag*)(BTl + boff);
      acc[ct] = __builtin_amdgcn_mfma_f32_16x16x32_bf16(ah, bh, acc[ct], 0, 0, 0);
      acc[ct] = __builtin_amdgcn_mfma_f32_16x16x32_bf16(ah, bl, acc[ct], 0, 0, 0);
      acc[ct] = __builtin_amdgcn_mfma_f32_16x16x32_bf16(al, bh, acc[ct], 0, 0, 0);
    }
  }
  int rbase = r0 + (l >> 4) * 4;
#pragma unroll
  for (int ct = 0; ct < 8; ct++) {
    int col = ct * 16 + (l & 15);
#pragma unroll
    for (int r = 0; r < 4; r++) {
      int row = rbase + r;
      if (row < nrows) Y[(size_t)row * FDIM + col] = acc[ct][r];
    }
  }
}

// ---------------- GCN gather (CSR payload) + ReLU + fused epilogues ----------
// FUSE=0: write h1, compute layer-2 score+hist.  FUSE=1: final MLP to out.

template <int FUSE>
__global__ void k_gather(const float* __restrict__ xw, const float* __restrict__ dinv,
                         const int* __restrict__ rstart, const int* __restrict__ rcnt,
                         const int2* __restrict__ pay, float* __restrict__ outH,
                         float* __restrict__ outF,
                         const float* __restrict__ p2, const float* __restrict__ invn2,
                         float* __restrict__ sc, int* __restrict__ hist,
                         const float* __restrict__ vvec, const float* __restrict__ cc,
                         int n) {
  int wv = threadIdx.x >> 6, l = threadIdx.x & 63;
  int c = blockIdx.x * 4 + wv;
  if (c >= n) return;
  float dc = dinv[c];
  float2 v = ((const float2*)(xw + (size_t)c * FDIM))[l];
  float ax = dc * dc * v.x, ay = dc * dc * v.y;
  int st = rstart[c], cn = rcnt[c];
  for (int q0 = 0; q0 < cn; q0 += 64) {
    int2 ep = (q0 + l < cn) ? pay[st + q0 + l] : make_int2(0, 0);
    int m = min(64, cn - q0);
    for (int q = 0; q < m; q++) {
      int r = __shfl(ep.x, q, 64);
      float nm = __int_as_float(__shfl(ep.y, q, 64));
      float2 s = ((const float2*)(xw + (size_t)r * FDIM))[l];
      ax += nm * s.x; ay += nm * s.y;
    }
  }
  float r0 = fmaxf(ax, 0.0f), r1 = fmaxf(ay, 0.0f);
  if (FUSE == 0) {
    ((float2*)(outH + (size_t)c * FDIM))[l] = make_float2(r0, r1);
    float2 pv = ((const float2*)p2)[l];
    float s = r0 * pv.x + r1 * pv.y;
    s = wave_sum(s);
    if (l == 0) {
      s *= invn2[0];
      sc[c] = s;
      atomicAdd(&hist[omap(s) >> 16], 1);
    }
  } else {
    float2 vv = ((const float2*)vvec)[l];
    float s = r0 * vv.x + r1 * vv.y;
    s = wave_sum(s);
    if (l == 0) outF[c] = s + cc[0];
  }
}

// ---------------------------------------------------------------------------

extern "C" void kernel_launch(void* const* d_in, const int* in_sizes, int n_in,
                              void* d_out, int out_size, void* d_ws, size_t ws_size,
                              hipStream_t stream) {
  const float* x    = (const float*)d_in[0];
  const int*   ei   = (const int*)d_in[1];
  const float* ew   = (const float*)d_in[2];
  const float* p1   = (const float*)d_in[3];
  const float* wih1 = (const float*)d_in[4];
  const float* whh1 = (const float*)d_in[5];
  const float* bih1 = (const float*)d_in[6];
  const float* bhh1 = (const float*)d_in[7];
  const float* h01  = (const float*)d_in[8];
  const float* p2   = (const float*)d_in[9];
  const float* wih2 = (const float*)d_in[10];
  const float* whh2 = (const float*)d_in[11];
  const float* bih2 = (const float*)d_in[12];
  const float* bhh2 = (const float*)d_in[13];
  const float* h02  = (const float*)d_in[14];
  const float* l1w  = (const float*)d_in[15];
  const float* l1b  = (const float*)d_in[16];
  const float* l2w  = (const float*)d_in[17];
  const float* l2b  = (const float*)d_in[18];
  float* out = (float*)d_out;

  const int N = in_sizes[0] / FDIM;
  const int E = in_sizes[2];

  // workspace layout
  size_t off = 0;
  auto alloc = [&](size_t bytes) -> char* {
    char* p = (char*)d_ws + off;
    off = (off + bytes + 255) & ~(size_t)255;
    return p;
  };
  float* scores = (float*)alloc((size_t)N * 4);
  unsigned long long* candk = (unsigned long long*)alloc(4096 * 8);
  int*   tidx  = (int*)alloc(128 * 4);
  float* ttanh = (float*)alloc(128 * 4);
  float* invn1 = (float*)alloc(4);
  float* invn2 = (float*)alloc(4);
  float* deg   = (float*)alloc((size_t)N * 4);   // aliased by hist after k_dinv
  float* dinv  = (float*)alloc((size_t)N * 4);
  int*   cnt   = (int*)alloc((size_t)N * 4);
  int*   rstart= (int*)alloc((size_t)N * 4);
  int*   rnext = (int*)alloc((size_t)N * 4);
  const int nb = (N + 1023) / 1024;
  int*   bsum  = (int*)alloc((size_t)nb * 4);
  int2*  pay   = (int2*)alloc((size_t)E * 8);
  float* vvec  = (float*)alloc(128 * 4);
  float* cc    = (float*)alloc(4);
  unsigned short* WTh = (unsigned short*)alloc(128 * 128 * 2);
  unsigned short* WTl = (unsigned short*)alloc(128 * 128 * 2);
  float* xw    = (float*)alloc((size_t)N * FDIM * 4);
  float* h1    = (float*)alloc((size_t)N * FDIM * 4);
  (void)ws_size; (void)n_in; (void)out_size;

  int* hist = (int*)deg;          // 65536 bins + csel, fits in deg's N*4 bytes
  int* csel = hist + 65536;       // csel+1 = thrb scratch (outside k_zero range)

  const int gemmblocks = ((N + 15) / 16 + 3) / 4;

  // ---- setup: degrees + CSR payload (shared by both layers) ----
  k_init_degcnt<<<(N + 255) / 256, 256, 0, stream>>>(deg, cnt, N);
  k_edge_deg<<<(E + 255) / 256, 256, 0, stream>>>(ei, ew, deg, cnt, E);
  k_dinv<<<(N + 255) / 256, 256, 0, stream>>>(deg, dinv, N);
  k_scan1<<<nb, 256, 0, stream>>>(cnt, bsum, N);
  k_scan2<<<1, 64, 0, stream>>>(bsum, nb);
  k_scan3<<<nb, 1024, 0, stream>>>(cnt, bsum, rstart, rnext, N);
  k_fill<<<(E + 255) / 256, 256, 0, stream>>>(ei, ew, dinv, rnext, pay, E);
  k_linfuse<<<1, 128, 0, stream>>>(l1w, l1b, l2w, l2b, vvec, cc);
  k_invnorm<<<1, 64, 0, stream>>>(p1, invn1);
  k_invnorm<<<1, 64, 0, stream>>>(p2, invn2);

  // ---- layer 1 ----
  k_zero<<<257, 256, 0, stream>>>(hist);
  k_score<<<(N + 3) / 4, 256, 0, stream>>>(x, p1, invn1, scores, hist, N);
  k_findthr<<<1, 1024, 0, stream>>>(hist, csel + 1);
  k_collect<<<(N + 255) / 256, 256, 0, stream>>>(scores, csel + 1, candk, csel, N);
  k_sel<<<1, 1024, 0, stream>>>(candk, csel, tidx, ttanh);
  k_gru<<<128, 384, 0, stream>>>(x, tidx, ttanh, wih1, whh1, bih1, bhh1, h01, WTh, WTl);
  k_gemm3<<<gemmblocks, 256, 0, stream>>>(x, WTh, WTl, xw, N);
  k_zero<<<257, 256, 0, stream>>>(hist);
  k_gather<0><<<(N + 3) / 4, 256, 0, stream>>>(xw, dinv, rstart, cnt, pay, h1, nullptr,
                                               p2, invn2, scores, hist, nullptr, nullptr, N);

  // ---- layer 2 + fused final linear ----
  k_findthr<<<1, 1024, 0, stream>>>(hist, csel + 1);
  k_collect<<<(N + 255) / 256, 256, 0, stream>>>(scores, csel + 1, candk, csel, N);
  k_sel<<<1, 1024, 0, stream>>>(candk, csel, tidx, ttanh);
  k_gru<<<128, 384, 0, stream>>>(h1, tidx, ttanh, wih2, whh2, bih2, bhh2, h02, WTh, WTl);
  k_gemm3<<<gemmblocks, 256, 0, stream>>>(h1, WTh, WTl, xw, N);
  k_gather<1><<<(N + 3) / 4, 256, 0, stream>>>(xw, dinv, rstart, cnt, pay, nullptr, out,
                                               nullptr, nullptr, nullptr, nullptr, vvec, cc, N);
}